// Round 5
// baseline (205.824 us; speedup 1.0000x reference)
//
#include <hip/hip_runtime.h>

#define M_ANT 64
#define POWER_CONSTR 1.0f

typedef float f32x4 __attribute__((ext_vector_type(4)));

// ---------------------------------------------------------------------------
// Kernel 1: per-block partial energies per antenna — fully coalesced.
// Flat idx = b*2048 + half*1024 + a*16 + k, so float4 index f belongs to
// antenna (f>>2)&63. Grid stride is a multiple of 256 float4s so each
// thread's antenna is FIXED. Lane i loads float4 at base+i -> 16B/lane,
// perfectly coalesced. 4-deep unroll (8-deep measured WORSE, R4: 192 vs 176).
// Block combine: fixed-order LDS sum (deterministic, no float atomics).
// ---------------------------------------------------------------------------
__global__ __launch_bounds__(256) void energy_partial(
    const f32x4* __restrict__ P4, float* __restrict__ partials, int nvec) {
  const int tid = threadIdx.x;
  const int gtid = blockIdx.x * 256 + tid;
  const int stride = gridDim.x * 256;

  float acc = 0.0f;
  int f = gtid;
  for (; f + 3 * stride < nvec; f += 4 * stride) {
    f32x4 a = P4[f];
    f32x4 b = P4[f + stride];
    f32x4 c = P4[f + 2 * stride];
    f32x4 d = P4[f + 3 * stride];
    acc += a.x * a.x + a.y * a.y + a.z * a.z + a.w * a.w;
    acc += b.x * b.x + b.y * b.y + b.z * b.z + b.w * b.w;
    acc += c.x * c.x + c.y * c.y + c.z * c.z + c.w * c.w;
    acc += d.x * d.x + d.y * d.y + d.z * d.z + d.w * d.w;
  }
  for (; f < nvec; f += stride) {
    f32x4 v = P4[f];
    acc += v.x * v.x + v.y * v.y + v.z * v.z + v.w * v.w;
  }

  __shared__ float part[256];
  part[tid] = acc;
  __syncthreads();
  if (tid < 64) {
    // threads 4a..4a+3 all hold antenna a
    float s = (part[4 * tid] + part[4 * tid + 1]) +
              (part[4 * tid + 2] + part[4 * tid + 3]);
    partials[blockIdx.x * 64 + tid] = s;
  }
}

// ---------------------------------------------------------------------------
// Kernel 2: reduce partials[nblocks][64] -> scale[64].
// 1 block x 1024 threads: thread (j=tid>>6, a=tid&63) sums blocks b===j (mod 16)
// -> coalesced 256B wave reads, 16-way MLP. Fixed-order LDS tree over j.
// ---------------------------------------------------------------------------
__global__ __launch_bounds__(1024) void energy_finalize(
    const float* __restrict__ partials, float* __restrict__ scale, int nblocks) {
  const int tid = threadIdx.x;
  const int a = tid & 63;
  const int j = tid >> 6;  // 0..15
  float s = 0.0f;
  for (int b = j; b < nblocks; b += 16) s += partials[b * 64 + a];
  __shared__ float part[1024];
  part[tid] = s;
  __syncthreads();
  if (tid < 512) part[tid] += part[tid + 512];
  __syncthreads();
  if (tid < 256) part[tid] += part[tid + 256];
  __syncthreads();
  if (tid < 128) part[tid] += part[tid + 128];
  __syncthreads();
  if (tid < 64) {
    const float energy = part[tid] + part[tid + 64];
    scale[tid] = sqrtf(POWER_CONSTR / energy);
  }
}

// ---------------------------------------------------------------------------
// Kernel 3: out = P * scale[antenna]. Coalesced float4 grid-stride; antenna
// fixed per thread = (tid>>2)&63. PLAIN stores this round (A/B vs R3's
// nontemporal: isolating whether the nt bit was throttling write BW).
// ---------------------------------------------------------------------------
__global__ __launch_bounds__(256) void apply_scale(
    const f32x4* __restrict__ P4, const float* __restrict__ scale,
    f32x4* __restrict__ O4, int nvec) {
  __shared__ float s_scale[M_ANT];
  if (threadIdx.x < M_ANT) s_scale[threadIdx.x] = scale[threadIdx.x];
  __syncthreads();

  const int gtid = blockIdx.x * 256 + threadIdx.x;
  const int stride = gridDim.x * 256;
  // antenna fixed per thread (stride multiple of 256 float4s)
  const float sc = s_scale[(threadIdx.x >> 2) & 63];

  for (int f = gtid; f < nvec; f += stride) {
    f32x4 v = P4[f];
    v *= sc;
    O4[f] = v;
  }
}

extern "C" void kernel_launch(void* const* d_in, const int* in_sizes, int n_in,
                              void* d_out, int out_size, void* d_ws, size_t ws_size,
                              hipStream_t stream) {
  const f32x4* P4 = (const f32x4*)d_in[0];
  f32x4* O4 = (f32x4*)d_out;
  float* ws = (float*)d_ws;

  const int nelem = in_sizes[0];  // B * 2*M*K = 67,108,864
  const int nvec = nelem / 4;     // float4 count

  // Partial-reduction grid: 2048 blocks (8 blocks/CU), clamped to ws capacity.
  int nblocks1 = 2048;
  const size_t ws_floats = ws_size / sizeof(float);
  if (ws_floats < (size_t)nblocks1 * 64 + 64) {
    size_t cap = ws_floats > 64 ? (ws_floats - 64) / 64 : 1;
    nblocks1 = (int)(cap < 1 ? 1 : cap);
  }
  if (nblocks1 > (nvec + 255) / 256) nblocks1 = (nvec + 255) / 256;

  float* partials = ws;                       // nblocks1 * 64 floats
  float* scale = ws + (size_t)nblocks1 * 64;  // 64 floats

  energy_partial<<<nblocks1, 256, 0, stream>>>(P4, partials, nvec);
  energy_finalize<<<1, 1024, 0, stream>>>(partials, scale, nblocks1);

  int nblocks3 = (nvec + 255) / 256;
  if (nblocks3 > 2048) nblocks3 = 2048;
  apply_scale<<<nblocks3, 256, 0, stream>>>(P4, scale, O4, nvec);
}

// Round 6
// 174.432 us; speedup vs baseline: 1.1800x; 1.1800x over previous
//
#include <hip/hip_runtime.h>

#define M_ANT 64
#define POWER_CONSTR 1.0f

typedef float f32x4 __attribute__((ext_vector_type(4)));

// ---------------------------------------------------------------------------
// Kernel 1: per-block partial energies per antenna — fully coalesced.
// Flat idx = b*2048 + half*1024 + a*16 + k, so float4 index f belongs to
// antenna (f>>2)&63. Grid stride is a multiple of 256 float4s so each
// thread's antenna is FIXED. Lane i loads float4 at base+i -> 16B/lane,
// perfectly coalesced. 4-deep unroll (8-deep measured WORSE, R4: 192 vs 176).
// FORWARD sweep: slab k = [k*8MB, (k+1)*8MB) touched in increasing k.
// Block combine: fixed-order LDS sum (deterministic, no float atomics).
// ---------------------------------------------------------------------------
__global__ __launch_bounds__(256) void energy_partial(
    const f32x4* __restrict__ P4, float* __restrict__ partials, int nvec) {
  const int tid = threadIdx.x;
  const int gtid = blockIdx.x * 256 + tid;
  const int stride = gridDim.x * 256;

  float acc = 0.0f;
  int f = gtid;
  for (; f + 3 * stride < nvec; f += 4 * stride) {
    f32x4 a = P4[f];
    f32x4 b = P4[f + stride];
    f32x4 c = P4[f + 2 * stride];
    f32x4 d = P4[f + 3 * stride];
    acc += a.x * a.x + a.y * a.y + a.z * a.z + a.w * a.w;
    acc += b.x * b.x + b.y * b.y + b.z * b.z + b.w * b.w;
    acc += c.x * c.x + c.y * c.y + c.z * c.z + c.w * c.w;
    acc += d.x * d.x + d.y * d.y + d.z * d.z + d.w * d.w;
  }
  for (; f < nvec; f += stride) {
    f32x4 v = P4[f];
    acc += v.x * v.x + v.y * v.y + v.z * v.z + v.w * v.w;
  }

  __shared__ float part[256];
  part[tid] = acc;
  __syncthreads();
  if (tid < 64) {
    // threads 4a..4a+3 all hold antenna a
    float s = (part[4 * tid] + part[4 * tid + 1]) +
              (part[4 * tid + 2] + part[4 * tid + 3]);
    partials[blockIdx.x * 64 + tid] = s;
  }
}

// ---------------------------------------------------------------------------
// Kernel 2: reduce partials[nblocks][64] -> scale[64].
// 1 block x 1024 threads: thread (j=tid>>6, a=tid&63) sums blocks b===j (mod 16)
// -> coalesced 256B wave reads, 16-way MLP. Fixed-order LDS tree over j.
// ---------------------------------------------------------------------------
__global__ __launch_bounds__(1024) void energy_finalize(
    const float* __restrict__ partials, float* __restrict__ scale, int nblocks) {
  const int tid = threadIdx.x;
  const int a = tid & 63;
  const int j = tid >> 6;  // 0..15
  float s = 0.0f;
  for (int b = j; b < nblocks; b += 16) s += partials[b * 64 + a];
  __shared__ float part[1024];
  part[tid] = s;
  __syncthreads();
  if (tid < 512) part[tid] += part[tid + 512];
  __syncthreads();
  if (tid < 256) part[tid] += part[tid + 256];
  __syncthreads();
  if (tid < 128) part[tid] += part[tid + 128];
  __syncthreads();
  if (tid < 64) {
    const float energy = part[tid] + part[tid + 64];
    scale[tid] = sqrtf(POWER_CONSTR / energy);
  }
}

// ---------------------------------------------------------------------------
// Kernel 3: out = P * scale[antenna]. Coalesced float4, antenna fixed per
// thread, nontemporal stores (R5 A/B: plain stores +30us — nt stores keep
// dirty output out of L3).
// REVERSE sweep (k descending): pass1 leaves slab 31 youngest in L3; reading
// most-recently-used first is LRU-optimal -> re-read becomes L3 hits instead
// of cyclic thrash. Also ends with slab 0 youngest = where the next replay's
// pass1 starts.
// ---------------------------------------------------------------------------
__global__ __launch_bounds__(256) void apply_scale(
    const f32x4* __restrict__ P4, const float* __restrict__ scale,
    f32x4* __restrict__ O4, int nvec) {
  __shared__ float s_scale[M_ANT];
  if (threadIdx.x < M_ANT) s_scale[threadIdx.x] = scale[threadIdx.x];
  __syncthreads();

  const int gtid = blockIdx.x * 256 + threadIdx.x;
  const int stride = gridDim.x * 256;
  // antenna fixed per thread (stride multiple of 256 float4s)
  const float sc = s_scale[(threadIdx.x >> 2) & 63];

  if (gtid < nvec) {
    int k = (nvec - 1 - gtid) / stride;  // last iteration index for this thread
    for (; k >= 0; --k) {
      const int f = gtid + k * stride;
      f32x4 v = P4[f];
      v *= sc;
      __builtin_nontemporal_store(v, &O4[f]);
    }
  }
}

extern "C" void kernel_launch(void* const* d_in, const int* in_sizes, int n_in,
                              void* d_out, int out_size, void* d_ws, size_t ws_size,
                              hipStream_t stream) {
  const f32x4* P4 = (const f32x4*)d_in[0];
  f32x4* O4 = (f32x4*)d_out;
  float* ws = (float*)d_ws;

  const int nelem = in_sizes[0];  // B * 2*M*K = 67,108,864
  const int nvec = nelem / 4;     // float4 count

  // Partial-reduction grid: 2048 blocks (8 blocks/CU), clamped to ws capacity.
  int nblocks1 = 2048;
  const size_t ws_floats = ws_size / sizeof(float);
  if (ws_floats < (size_t)nblocks1 * 64 + 64) {
    size_t cap = ws_floats > 64 ? (ws_floats - 64) / 64 : 1;
    nblocks1 = (int)(cap < 1 ? 1 : cap);
  }
  if (nblocks1 > (nvec + 255) / 256) nblocks1 = (nvec + 255) / 256;

  float* partials = ws;                       // nblocks1 * 64 floats
  float* scale = ws + (size_t)nblocks1 * 64;  // 64 floats

  energy_partial<<<nblocks1, 256, 0, stream>>>(P4, partials, nvec);
  energy_finalize<<<1, 1024, 0, stream>>>(partials, scale, nblocks1);

  int nblocks3 = (nvec + 255) / 256;
  if (nblocks3 > 2048) nblocks3 = 2048;
  apply_scale<<<nblocks3, 256, 0, stream>>>(P4, scale, O4, nvec);
}

// Round 7
// 168.711 us; speedup vs baseline: 1.2200x; 1.0339x over previous
//
#include <hip/hip_runtime.h>

#define M_ANT 64
#define POWER_CONSTR 1.0f

typedef float f32x4 __attribute__((ext_vector_type(4)));

// ---------------------------------------------------------------------------
// Kernel 1: per-block partial energies per antenna — fully coalesced.
// Flat idx = b*2048 + half*1024 + a*16 + k, so float4 index f belongs to
// antenna (f>>2)&63. Grid stride is a multiple of 256 float4s so each
// thread's antenna is FIXED. Lane i loads float4 at base+i -> 16B/lane,
// perfectly coalesced. 4-deep unroll (8-deep measured WORSE, R4: 192 vs 176).
// Block combine: fixed-order LDS sum (deterministic, no float atomics).
// ---------------------------------------------------------------------------
__global__ __launch_bounds__(256) void energy_partial(
    const f32x4* __restrict__ P4, float* __restrict__ partials, int nvec) {
  const int tid = threadIdx.x;
  const int gtid = blockIdx.x * 256 + tid;
  const int stride = gridDim.x * 256;

  float acc = 0.0f;
  int f = gtid;
  for (; f + 3 * stride < nvec; f += 4 * stride) {
    f32x4 a = P4[f];
    f32x4 b = P4[f + stride];
    f32x4 c = P4[f + 2 * stride];
    f32x4 d = P4[f + 3 * stride];
    acc += a.x * a.x + a.y * a.y + a.z * a.z + a.w * a.w;
    acc += b.x * b.x + b.y * b.y + b.z * b.z + b.w * b.w;
    acc += c.x * c.x + c.y * c.y + c.z * c.z + c.w * c.w;
    acc += d.x * d.x + d.y * d.y + d.z * d.z + d.w * d.w;
  }
  for (; f < nvec; f += stride) {
    f32x4 v = P4[f];
    acc += v.x * v.x + v.y * v.y + v.z * v.z + v.w * v.w;
  }

  __shared__ float part[256];
  part[tid] = acc;
  __syncthreads();
  if (tid < 64) {
    // threads 4a..4a+3 all hold antenna a
    float s = (part[4 * tid] + part[4 * tid + 1]) +
              (part[4 * tid + 2] + part[4 * tid + 3]);
    partials[blockIdx.x * 64 + tid] = s;
  }
}

// ---------------------------------------------------------------------------
// Kernel 2: reduce partials[nblocks][64] -> scale[64].
// 1 block x 1024 threads: thread (j=tid>>6, a=tid&63) sums blocks b===j (mod 16)
// -> coalesced 256B wave reads, 16-way MLP. Fixed-order LDS tree over j.
// ---------------------------------------------------------------------------
__global__ __launch_bounds__(1024) void energy_finalize(
    const float* __restrict__ partials, float* __restrict__ scale, int nblocks) {
  const int tid = threadIdx.x;
  const int a = tid & 63;
  const int j = tid >> 6;  // 0..15
  float s = 0.0f;
  for (int b = j; b < nblocks; b += 16) s += partials[b * 64 + a];
  __shared__ float part[1024];
  part[tid] = s;
  __syncthreads();
  if (tid < 512) part[tid] += part[tid + 512];
  __syncthreads();
  if (tid < 256) part[tid] += part[tid + 256];
  __syncthreads();
  if (tid < 128) part[tid] += part[tid + 128];
  __syncthreads();
  if (tid < 64) {
    const float energy = part[tid] + part[tid + 64];
    scale[tid] = sqrtf(POWER_CONSTR / energy);
  }
}

// ---------------------------------------------------------------------------
// Kernel 3: out = P * scale[antenna]. Coalesced float4, antenna fixed per
// thread. BOTH streams non-temporal this round: R5 proved nt stores help
// (+30us vs plain); R6 proved the input does NOT survive in L3 (reverse
// sweep = noise), so the pass-3 read has zero reuse too — let neither
// stream allocate in L2/L3 and stop the two-stream thrash.
// Reverse sweep kept from R6 (neutral, free).
// ---------------------------------------------------------------------------
__global__ __launch_bounds__(256) void apply_scale(
    const f32x4* __restrict__ P4, const float* __restrict__ scale,
    f32x4* __restrict__ O4, int nvec) {
  __shared__ float s_scale[M_ANT];
  if (threadIdx.x < M_ANT) s_scale[threadIdx.x] = scale[threadIdx.x];
  __syncthreads();

  const int gtid = blockIdx.x * 256 + threadIdx.x;
  const int stride = gridDim.x * 256;
  // antenna fixed per thread (stride multiple of 256 float4s)
  const float sc = s_scale[(threadIdx.x >> 2) & 63];

  if (gtid < nvec) {
    int k = (nvec - 1 - gtid) / stride;  // last iteration index for this thread
    for (; k >= 0; --k) {
      const int f = gtid + k * stride;
      f32x4 v = __builtin_nontemporal_load(&P4[f]);
      v *= sc;
      __builtin_nontemporal_store(v, &O4[f]);
    }
  }
}

extern "C" void kernel_launch(void* const* d_in, const int* in_sizes, int n_in,
                              void* d_out, int out_size, void* d_ws, size_t ws_size,
                              hipStream_t stream) {
  const f32x4* P4 = (const f32x4*)d_in[0];
  f32x4* O4 = (f32x4*)d_out;
  float* ws = (float*)d_ws;

  const int nelem = in_sizes[0];  // B * 2*M*K = 67,108,864
  const int nvec = nelem / 4;     // float4 count

  // Partial-reduction grid: 2048 blocks (8 blocks/CU), clamped to ws capacity.
  int nblocks1 = 2048;
  const size_t ws_floats = ws_size / sizeof(float);
  if (ws_floats < (size_t)nblocks1 * 64 + 64) {
    size_t cap = ws_floats > 64 ? (ws_floats - 64) / 64 : 1;
    nblocks1 = (int)(cap < 1 ? 1 : cap);
  }
  if (nblocks1 > (nvec + 255) / 256) nblocks1 = (nvec + 255) / 256;

  float* partials = ws;                       // nblocks1 * 64 floats
  float* scale = ws + (size_t)nblocks1 * 64;  // 64 floats

  energy_partial<<<nblocks1, 256, 0, stream>>>(P4, partials, nvec);
  energy_finalize<<<1, 1024, 0, stream>>>(partials, scale, nblocks1);

  int nblocks3 = (nvec + 255) / 256;
  if (nblocks3 > 2048) nblocks3 = 2048;
  apply_scale<<<nblocks3, 256, 0, stream>>>(P4, scale, O4, nvec);
}